// Round 1
// baseline (838.930 us; speedup 1.0000x reference)
//
#include <hip/hip_runtime.h>
#include <math.h>

#define NSITES 100000
#define NYEARS 20
#define NVIS 2
#define HDIM 64

__device__ __forceinline__ float sigmoidf_(float x) {
    return 1.0f / (1.0f + __expf(-x));
}

__device__ __forceinline__ float eluf_(float x) {
    return x > 0.0f ? x : expm1f(x);
}

// One thread = one site. All weight reads are wave-uniform -> SMEM (s_load),
// hidden state lives in 64 VGPRs, matvec is 4096 fully-unrolled v_fma_f32
// with one SGPR operand each. VALU-bound by design.
__global__ __launch_bounds__(256, 2)
void rnet_kernel(const float* __restrict__ sxy0,
                 const float* __restrict__ sxy,
                 const float* __restrict__ oxy,
                 const float* __restrict__ W_h0, const float* __restrict__ b_h0,
                 const float* __restrict__ W_h1, const float* __restrict__ b_h1,
                 const float* __restrict__ W_ih, const float* __restrict__ b_ih,
                 const float* __restrict__ W_hh, const float* __restrict__ b_hh,
                 const float* __restrict__ W_psi0, const float* __restrict__ b_psi0,
                 const float* __restrict__ W_psi, const float* __restrict__ b_psi,
                 const float* __restrict__ W_p, const float* __restrict__ b_p,
                 float* __restrict__ out)
{
    const int site = blockIdx.x * blockDim.x + threadIdx.x;
    if (site >= NSITES) return;

    float* __restrict__ out_psi0 = out;                  // [N]
    float* __restrict__ out_psi  = out + NSITES;         // [N,19]
    float* __restrict__ out_p    = out + 20 * NSITES;    // [N,20,2]

    const float s0 = sxy0[site];

    // hs = elu(s0 * W_h0 + b_h0)
    float hs[HDIM];
#pragma unroll
    for (int r = 0; r < HDIM; ++r) {
        hs[r] = eluf_(fmaf(s0, W_h0[r], b_h0[r]));
    }

    // h0 = elu(W_h1 @ hs + b_h1)
    float h[HDIM];
#pragma unroll
    for (int r = 0; r < HDIM; ++r) {
        float acc = b_h1[r];
#pragma unroll
        for (int k = 0; k < HDIM; ++k)
            acc = fmaf(W_h1[r * HDIM + k], hs[k], acc);
        h[r] = eluf_(acc);
    }

    // psi0 = sigmoid(W_psi0 . h0 + b_psi0)
    {
        float acc = b_psi0[0];
#pragma unroll
        for (int k = 0; k < HDIM; ++k)
            acc = fmaf(W_psi0[k], h[k], acc);
        out_psi0[site] = sigmoidf_(acc);
    }

    const float wpo = W_p[HDIM];   // scalar weight on oxy
    // p at t = 0 (uses h0)
    {
        float pb = b_p[0];
#pragma unroll
        for (int k = 0; k < HDIM; ++k)
            pb = fmaf(W_p[k], h[k], pb);
#pragma unroll
        for (int j = 0; j < NVIS; ++j) {
            const float o = oxy[site * (NYEARS * NVIS) + j];
            out_p[site * (NYEARS * NVIS) + j] = sigmoidf_(fmaf(o, wpo, pb));
        }
    }

    // RNN: h_t = relu(x_t * W_ih + b_ih + W_hh @ h_{t-1} + b_hh), t = 1..19
    for (int t = 1; t < NYEARS; ++t) {
        const float x = sxy[site * (NYEARS - 1) + (t - 1)];

        float hn[HDIM];
#pragma unroll
        for (int r = 0; r < HDIM; ++r) {
            float acc = fmaf(x, W_ih[r], b_ih[r] + b_hh[r]);
#pragma unroll
            for (int k = 0; k < HDIM; ++k)
                acc = fmaf(W_hh[r * HDIM + k], h[k], acc);
            hn[r] = acc > 0.0f ? acc : 0.0f;
        }
#pragma unroll
        for (int r = 0; r < HDIM; ++r) h[r] = hn[r];

        // psi[t-1] = sigmoid(W_psi . h + b_psi)
        float accp = b_psi[0];
#pragma unroll
        for (int k = 0; k < HDIM; ++k)
            accp = fmaf(W_psi[k], h[k], accp);
        out_psi[site * (NYEARS - 1) + (t - 1)] = sigmoidf_(accp);

        // p[t] = sigmoid(W_p[:64] . h + oxy * W_p[64] + b_p)
        float pb = b_p[0];
#pragma unroll
        for (int k = 0; k < HDIM; ++k)
            pb = fmaf(W_p[k], h[k], pb);
#pragma unroll
        for (int j = 0; j < NVIS; ++j) {
            const float o = oxy[site * (NYEARS * NVIS) + t * NVIS + j];
            out_p[site * (NYEARS * NVIS) + t * NVIS + j] = sigmoidf_(fmaf(o, wpo, pb));
        }
    }
}

extern "C" void kernel_launch(void* const* d_in, const int* in_sizes, int n_in,
                              void* d_out, int out_size, void* d_ws, size_t ws_size,
                              hipStream_t stream) {
    const float* sxy0   = (const float*)d_in[0];
    const float* sxy    = (const float*)d_in[1];
    const float* oxy    = (const float*)d_in[2];
    const float* W_h0   = (const float*)d_in[3];
    const float* b_h0   = (const float*)d_in[4];
    const float* W_h1   = (const float*)d_in[5];
    const float* b_h1   = (const float*)d_in[6];
    const float* W_ih   = (const float*)d_in[7];
    const float* b_ih   = (const float*)d_in[8];
    const float* W_hh   = (const float*)d_in[9];
    const float* b_hh   = (const float*)d_in[10];
    const float* W_psi0 = (const float*)d_in[11];
    const float* b_psi0 = (const float*)d_in[12];
    const float* W_psi  = (const float*)d_in[13];
    const float* b_psi  = (const float*)d_in[14];
    const float* W_p    = (const float*)d_in[15];
    const float* b_p    = (const float*)d_in[16];

    float* out = (float*)d_out;

    dim3 block(256);
    dim3 grid((NSITES + 255) / 256);
    rnet_kernel<<<grid, block, 0, stream>>>(
        sxy0, sxy, oxy, W_h0, b_h0, W_h1, b_h1, W_ih, b_ih, W_hh, b_hh,
        W_psi0, b_psi0, W_psi, b_psi, W_p, b_p, out);
}

// Round 3
// 219.800 us; speedup vs baseline: 3.8168x; 3.8168x over previous
//
#include <hip/hip_runtime.h>
#include <math.h>

#define NSITES 100000
#define NYEARS 20
#define HDIM 64

typedef __bf16 bf16x8 __attribute__((ext_vector_type(8)));
typedef float f32x4 __attribute__((ext_vector_type(4)));

__device__ __forceinline__ float sigmoidf_(float x) { return 1.0f / (1.0f + __expf(-x)); }
__device__ __forceinline__ float eluf_(float x) { return x > 0.0f ? x : expm1f(x); }

__device__ __forceinline__ unsigned pack2_(float a, float b) {
    union { __bf16 h; unsigned short u; } x, y;
    x.h = (__bf16)a; y.h = (__bf16)b;
    return ((unsigned)y.u << 16) | (unsigned)x.u;
}

// load 8 consecutive f32 (32B-aligned) -> bf16x8 (RNE via __bf16 cast)
__device__ __forceinline__ bf16x8 cvt8_(const float* p) {
    float4 a = ((const float4*)p)[0];
    float4 b = ((const float4*)p)[1];
    bf16x8 r;
    r[0] = (__bf16)a.x; r[1] = (__bf16)a.y; r[2] = (__bf16)a.z; r[3] = (__bf16)a.w;
    r[4] = (__bf16)b.x; r[5] = (__bf16)b.y; r[6] = (__bf16)b.z; r[7] = (__bf16)b.w;
    return r;
}

// read 8 bf16 from LDS (8B-aligned) -> bf16x8
__device__ __forceinline__ bf16x8 read_bfrag_(const unsigned short* hp) {
    union { bf16x8 v; uint2 u[2]; } r;
    r.u[0] = *(const uint2*)(hp);
    r.u[1] = *(const uint2*)(hp + 4);
    return r.v;
}

// One wave (64 thr) = 16 sites. MFMA 16x16x32 bf16:
//   A-frag: A[m=lane&15][k=quad*8+j]; B-frag: B[k=quad*8+j][n=lane&15]
//   D: row=quad*4+reg, col=lane&15
// Recurrence D[80x16] = Wcomb[80x64] @ h[64x16]; head rows 64..66 =
// W_psi, W_p[:64], W_psi0 with their biases folded into C-init.
// h round-trips D->B layout through a 2.1KB LDS buffer (stride 68 shorts).
__global__ __launch_bounds__(64, 4)
void rnet_kernel(const float* __restrict__ sxy0,
                 const float* __restrict__ sxy,
                 const float* __restrict__ oxy,
                 const float* __restrict__ W_h0, const float* __restrict__ b_h0,
                 const float* __restrict__ W_h1, const float* __restrict__ b_h1,
                 const float* __restrict__ W_ih, const float* __restrict__ b_ih,
                 const float* __restrict__ W_hh, const float* __restrict__ b_hh,
                 const float* __restrict__ W_psi0, const float* __restrict__ b_psi0,
                 const float* __restrict__ W_psi, const float* __restrict__ b_psi,
                 const float* __restrict__ W_p, const float* __restrict__ b_p,
                 float* __restrict__ out)
{
    const int lane = threadIdx.x;       // 0..63
    const int s = lane & 15;            // site within wave / A-row within tile
    const int q = lane >> 4;            // quad
    const int base = blockIdx.x * 16;   // NSITES = 6250*16 exactly
    const int site = base + s;

    __shared__ __align__(16) unsigned short h_sh[16 * 68];  // [site][row], stride 68 shorts = 136B
    __shared__ __align__(16) float psi_sh[16 * 19];
    __shared__ __align__(16) float p_sh[16 * 40];

    float* __restrict__ out_psi0 = out;                 // [N]
    float* __restrict__ out_psi  = out + NSITES;        // [N,19]
    float* __restrict__ out_p    = out + 20 * NSITES;   // [N,20,2]

    // ---- A-fragments (per-lane row m = lane&15 within each m-tile) ----
    bf16x8 a_hh[4][2], a_head[2], a_h1[4][2];
#pragma unroll
    for (int mt = 0; mt < 4; ++mt)
#pragma unroll
        for (int kt = 0; kt < 2; ++kt) {
            a_hh[mt][kt] = cvt8_(W_hh + (mt * 16 + s) * 64 + kt * 32 + q * 8);
            a_h1[mt][kt] = cvt8_(W_h1 + (mt * 16 + s) * 64 + kt * 32 + q * 8);
        }
    const float* hrow = (s == 1) ? W_p : ((s == 2) ? W_psi0 : W_psi);
#pragma unroll
    for (int kt = 0; kt < 2; ++kt) a_head[kt] = cvt8_(hrow + kt * 32 + q * 8);

    // ---- per-lane D-layout constants: rows mt*16 + q*4 + r ----
    f32x4 biasD[4], wihD[4], bh1D[4];
#pragma unroll
    for (int mt = 0; mt < 4; ++mt) {
        const int r0 = mt * 16 + q * 4;
        float4 bi = *(const float4*)(b_ih + r0);
        float4 bh = *(const float4*)(b_hh + r0);
        float4 wi = *(const float4*)(W_ih + r0);
        float4 b1 = *(const float4*)(b_h1 + r0);
        biasD[mt][0] = bi.x + bh.x; biasD[mt][1] = bi.y + bh.y;
        biasD[mt][2] = bi.z + bh.z; biasD[mt][3] = bi.w + bh.w;
        wihD[mt][0] = wi.x; wihD[mt][1] = wi.y; wihD[mt][2] = wi.z; wihD[mt][3] = wi.w;
        bh1D[mt][0] = b1.x; bh1D[mt][1] = b1.y; bh1D[mt][2] = b1.z; bh1D[mt][3] = b1.w;
    }
    f32x4 headC;
    headC[0] = (q == 0) ? b_psi[0]  : 0.0f;
    headC[1] = (q == 0) ? b_p[0]    : 0.0f;
    headC[2] = (q == 0) ? b_psi0[0] : 0.0f;
    headC[3] = 0.0f;
    const float wpo = W_p[HDIM];

    // ---- h0 round: hs = elu(s0*W_h0+b_h0) built directly in B-layout ----
    const float s0v = sxy0[site];
    bf16x8 bf0[2];
#pragma unroll
    for (int kt = 0; kt < 2; ++kt) {
        const float* wp = W_h0 + kt * 32 + q * 8;
        const float* bp = b_h0 + kt * 32 + q * 8;
        float4 w0 = ((const float4*)wp)[0], w1 = ((const float4*)wp)[1];
        float4 c0 = ((const float4*)bp)[0], c1 = ((const float4*)bp)[1];
        float v[8];
        v[0] = eluf_(fmaf(s0v, w0.x, c0.x)); v[1] = eluf_(fmaf(s0v, w0.y, c0.y));
        v[2] = eluf_(fmaf(s0v, w0.z, c0.z)); v[3] = eluf_(fmaf(s0v, w0.w, c0.w));
        v[4] = eluf_(fmaf(s0v, w1.x, c1.x)); v[5] = eluf_(fmaf(s0v, w1.y, c1.y));
        v[6] = eluf_(fmaf(s0v, w1.z, c1.z)); v[7] = eluf_(fmaf(s0v, w1.w, c1.w));
#pragma unroll
        for (int j = 0; j < 8; ++j) bf0[kt][j] = (__bf16)v[j];
    }
    {
        f32x4 acc[4];
#pragma unroll
        for (int mt = 0; mt < 4; ++mt) acc[mt] = bh1D[mt];
#pragma unroll
        for (int kt = 0; kt < 2; ++kt)
#pragma unroll
            for (int mt = 0; mt < 4; ++mt)
                acc[mt] = __builtin_amdgcn_mfma_f32_16x16x32_bf16(a_h1[mt][kt], bf0[kt], acc[mt], 0, 0, 0);
        // h0 = elu(acc); store to LDS in bf16
#pragma unroll
        for (int mt = 0; mt < 4; ++mt) {
            float v0 = eluf_(acc[mt][0]), v1 = eluf_(acc[mt][1]);
            float v2 = eluf_(acc[mt][2]), v3 = eluf_(acc[mt][3]);
            uint2 pk; pk.x = pack2_(v0, v1); pk.y = pack2_(v2, v3);
            *(uint2*)&h_sh[s * 68 + mt * 16 + q * 4] = pk;
        }
    }

    const float* sxy_l = sxy + (size_t)site * (NYEARS - 1);
    const float* oxy_l = oxy + (size_t)site * (NYEARS * 2);

    // ---- recurrence: round t computes h_t and heads(h_{t-1}) ----
    for (int t = 1; t < NYEARS; ++t) {
        bf16x8 bf[2];
        bf[0] = read_bfrag_(&h_sh[s * 68 + 0  + q * 8]);
        bf[1] = read_bfrag_(&h_sh[s * 68 + 32 + q * 8]);

        f32x4 acc[4], accH = headC;
#pragma unroll
        for (int mt = 0; mt < 4; ++mt) acc[mt] = biasD[mt];
#pragma unroll
        for (int kt = 0; kt < 2; ++kt) {
#pragma unroll
            for (int mt = 0; mt < 4; ++mt)
                acc[mt] = __builtin_amdgcn_mfma_f32_16x16x32_bf16(a_hh[mt][kt], bf[kt], acc[mt], 0, 0, 0);
            accH = __builtin_amdgcn_mfma_f32_16x16x32_bf16(a_head[kt], bf[kt], accH, 0, 0, 0);
        }

        const float x = sxy_l[t - 1];
#pragma unroll
        for (int mt = 0; mt < 4; ++mt) {
            float v0 = fmaxf(fmaf(x, wihD[mt][0], acc[mt][0]), 0.0f);
            float v1 = fmaxf(fmaf(x, wihD[mt][1], acc[mt][1]), 0.0f);
            float v2 = fmaxf(fmaf(x, wihD[mt][2], acc[mt][2]), 0.0f);
            float v3 = fmaxf(fmaf(x, wihD[mt][3], acc[mt][3]), 0.0f);
            uint2 pk; pk.x = pack2_(v0, v1); pk.y = pack2_(v2, v3);
            *(uint2*)&h_sh[s * 68 + mt * 16 + q * 4] = pk;
        }

        if (q == 0) {
            // accH[0]=W_psi.h_{t-1}+b_psi, [1]=W_p.h_{t-1}+b_p, [2]=W_psi0.h_{t-1}+b_psi0
            float2 ox = *(const float2*)(oxy_l + (t - 1) * 2);
            float p0 = sigmoidf_(fmaf(wpo, ox.x, accH[1]));
            float p1 = sigmoidf_(fmaf(wpo, ox.y, accH[1]));
            float2 pp; pp.x = p0; pp.y = p1;
            *(float2*)&p_sh[s * 40 + (t - 1) * 2] = pp;
            if (t == 1) {
                out_psi0[site] = sigmoidf_(accH[2]);   // psi0 from h0
            } else {
                psi_sh[s * 19 + (t - 2)] = sigmoidf_(accH[0]);
            }
        }
    }

    // ---- final heads on h_19 ----
    {
        bf16x8 bf[2];
        bf[0] = read_bfrag_(&h_sh[s * 68 + 0  + q * 8]);
        bf[1] = read_bfrag_(&h_sh[s * 68 + 32 + q * 8]);
        f32x4 accH = headC;
#pragma unroll
        for (int kt = 0; kt < 2; ++kt)
            accH = __builtin_amdgcn_mfma_f32_16x16x32_bf16(a_head[kt], bf[kt], accH, 0, 0, 0);
        if (q == 0) {
            float2 ox = *(const float2*)(oxy_l + 19 * 2);
            float p0 = sigmoidf_(fmaf(wpo, ox.x, accH[1]));
            float p1 = sigmoidf_(fmaf(wpo, ox.y, accH[1]));
            float2 pp; pp.x = p0; pp.y = p1;
            *(float2*)&p_sh[s * 40 + 38] = pp;
            psi_sh[s * 19 + 18] = sigmoidf_(accH[0]);
        }
    }

    __syncthreads();

    // ---- coalesced writeback from LDS ----
#pragma unroll
    for (int r = 0; r < 5; ++r) {
        int i = r * 64 + lane;
        if (i < 16 * 19) out_psi[(size_t)base * 19 + i] = psi_sh[i];
    }
    // p region per block: 16*40 = 640 floats = 160 float4
    f32x4* pg = (f32x4*)(out_p + (size_t)base * 40);
    const f32x4* ps = (const f32x4*)p_sh;
#pragma unroll
    for (int r = 0; r < 3; ++r) {
        int i = r * 64 + lane;
        if (i < 160) pg[i] = ps[i];
    }
}

extern "C" void kernel_launch(void* const* d_in, const int* in_sizes, int n_in,
                              void* d_out, int out_size, void* d_ws, size_t ws_size,
                              hipStream_t stream) {
    const float* sxy0   = (const float*)d_in[0];
    const float* sxy    = (const float*)d_in[1];
    const float* oxy    = (const float*)d_in[2];
    const float* W_h0   = (const float*)d_in[3];
    const float* b_h0   = (const float*)d_in[4];
    const float* W_h1   = (const float*)d_in[5];
    const float* b_h1   = (const float*)d_in[6];
    const float* W_ih   = (const float*)d_in[7];
    const float* b_ih   = (const float*)d_in[8];
    const float* W_hh   = (const float*)d_in[9];
    const float* b_hh   = (const float*)d_in[10];
    const float* W_psi0 = (const float*)d_in[11];
    const float* b_psi0 = (const float*)d_in[12];
    const float* W_psi  = (const float*)d_in[13];
    const float* b_psi  = (const float*)d_in[14];
    const float* W_p    = (const float*)d_in[15];
    const float* b_p    = (const float*)d_in[16];

    float* out = (float*)d_out;

    dim3 block(64);
    dim3 grid(NSITES / 16);   // 6250 waves, 16 sites each
    rnet_kernel<<<grid, block, 0, stream>>>(
        sxy0, sxy, oxy, W_h0, b_h0, W_h1, b_h1, W_ih, b_ih, W_hh, b_hh,
        W_psi0, b_psi0, W_psi, b_psi, W_p, b_p, out);
}

// Round 4
// 167.593 us; speedup vs baseline: 5.0058x; 1.3115x over previous
//
#include <hip/hip_runtime.h>
#include <math.h>

#define NSITES 100000
#define NYEARS 20
#define HDIM 64

typedef __bf16 bf16x8 __attribute__((ext_vector_type(8)));
typedef float f32x4 __attribute__((ext_vector_type(4)));

__device__ __forceinline__ float sigmoidf_(float x) { return 1.0f / (1.0f + __expf(-x)); }
__device__ __forceinline__ float eluf_(float x) { return x > 0.0f ? x : expm1f(x); }

__device__ __forceinline__ unsigned pack2_(float a, float b) {
    union { __bf16 h; unsigned short u; } x, y;
    x.h = (__bf16)a; y.h = (__bf16)b;
    return ((unsigned)y.u << 16) | (unsigned)x.u;
}

// load 8 consecutive f32 (32B-aligned) -> bf16x8 (RNE via __bf16 cast)
__device__ __forceinline__ bf16x8 cvt8_(const float* p) {
    float4 a = ((const float4*)p)[0];
    float4 b = ((const float4*)p)[1];
    bf16x8 r;
    r[0] = (__bf16)a.x; r[1] = (__bf16)a.y; r[2] = (__bf16)a.z; r[3] = (__bf16)a.w;
    r[4] = (__bf16)b.x; r[5] = (__bf16)b.y; r[6] = (__bf16)b.z; r[7] = (__bf16)b.w;
    return r;
}

// read 8 bf16 from LDS (8B-aligned) -> bf16x8
__device__ __forceinline__ bf16x8 read_bfrag_(const unsigned short* hp) {
    union { bf16x8 v; uint2 u[2]; } r;
    r.u[0] = *(const uint2*)(hp);
    r.u[1] = *(const uint2*)(hp + 4);
    return r.v;
}

// One wave (64 thr) = 16 sites. MFMA 16x16x32 bf16:
//   A-frag: A[m=lane&15][k=quad*8+j]; B-frag: B[k=quad*8+j][n=lane&15]
//   D: row=quad*4+reg, col=lane&15
// Recurrence D[80x16] = Wcomb[80x64] @ h[64x16]; head rows = W_psi, W_p[:64],
// W_psi0 with biases folded into C-init. h round-trips D->B layout through a
// 2.1KB LDS buffer (stride 68 shorts).
// __launch_bounds__(64,2): 256-reg unified budget. (64,4) capped at 128 regs
// and spilled 32KB/block of A-fragments to scratch -> 204MB HBM writes (R3).
__global__ __launch_bounds__(64, 2)
void rnet_kernel(const float* __restrict__ sxy0,
                 const float* __restrict__ sxy,
                 const float* __restrict__ oxy,
                 const float* __restrict__ W_h0, const float* __restrict__ b_h0,
                 const float* __restrict__ W_h1, const float* __restrict__ b_h1,
                 const float* __restrict__ W_ih, const float* __restrict__ b_ih,
                 const float* __restrict__ W_hh, const float* __restrict__ b_hh,
                 const float* __restrict__ W_psi0, const float* __restrict__ b_psi0,
                 const float* __restrict__ W_psi, const float* __restrict__ b_psi,
                 const float* __restrict__ W_p, const float* __restrict__ b_p,
                 float* __restrict__ out)
{
    const int lane = threadIdx.x;       // 0..63
    const int s = lane & 15;            // site within wave / A-row within tile
    const int q = lane >> 4;            // quad
    const int base = blockIdx.x * 16;   // NSITES = 6250*16 exactly
    const int site = base + s;

    __shared__ __align__(16) unsigned short h_sh[16 * 68];  // [site][row], stride 68 shorts
    __shared__ __align__(16) float psi_sh[16 * 19];
    __shared__ __align__(16) float p_sh[16 * 40];

    float* __restrict__ out_psi0 = out;                 // [N]
    float* __restrict__ out_psi  = out + NSITES;        // [N,19]
    float* __restrict__ out_p    = out + 20 * NSITES;   // [N,20,2]

    // ==== Stage 1: h0 (a_h1/bh1D live only here) ====
    {
        // hs = elu(s0*W_h0+b_h0), built directly in B-fragment layout
        const float s0v = sxy0[site];
        bf16x8 bf0[2];
#pragma unroll
        for (int kt = 0; kt < 2; ++kt) {
            const float* wp = W_h0 + kt * 32 + q * 8;
            const float* bp = b_h0 + kt * 32 + q * 8;
            float4 w0 = ((const float4*)wp)[0], w1 = ((const float4*)wp)[1];
            float4 c0 = ((const float4*)bp)[0], c1 = ((const float4*)bp)[1];
            float v[8];
            v[0] = eluf_(fmaf(s0v, w0.x, c0.x)); v[1] = eluf_(fmaf(s0v, w0.y, c0.y));
            v[2] = eluf_(fmaf(s0v, w0.z, c0.z)); v[3] = eluf_(fmaf(s0v, w0.w, c0.w));
            v[4] = eluf_(fmaf(s0v, w1.x, c1.x)); v[5] = eluf_(fmaf(s0v, w1.y, c1.y));
            v[6] = eluf_(fmaf(s0v, w1.z, c1.z)); v[7] = eluf_(fmaf(s0v, w1.w, c1.w));
#pragma unroll
            for (int j = 0; j < 8; ++j) bf0[kt][j] = (__bf16)v[j];
        }

        f32x4 acc[4];
#pragma unroll
        for (int mt = 0; mt < 4; ++mt) {
            float4 b1 = *(const float4*)(b_h1 + mt * 16 + q * 4);
            acc[mt][0] = b1.x; acc[mt][1] = b1.y; acc[mt][2] = b1.z; acc[mt][3] = b1.w;
        }
#pragma unroll
        for (int kt = 0; kt < 2; ++kt)
#pragma unroll
            for (int mt = 0; mt < 4; ++mt) {
                bf16x8 a = cvt8_(W_h1 + (mt * 16 + s) * 64 + kt * 32 + q * 8);
                acc[mt] = __builtin_amdgcn_mfma_f32_16x16x32_bf16(a, bf0[kt], acc[mt], 0, 0, 0);
            }
        // h0 = elu(acc); store to LDS in bf16
#pragma unroll
        for (int mt = 0; mt < 4; ++mt) {
            float v0 = eluf_(acc[mt][0]), v1 = eluf_(acc[mt][1]);
            float v2 = eluf_(acc[mt][2]), v3 = eluf_(acc[mt][3]);
            uint2 pk; pk.x = pack2_(v0, v1); pk.y = pack2_(v2, v3);
            *(uint2*)&h_sh[s * 68 + mt * 16 + q * 4] = pk;
        }
    }

    // ==== Stage 2: persistent loop state ====
    bf16x8 a_hh[4][2], a_head[2];
#pragma unroll
    for (int mt = 0; mt < 4; ++mt)
#pragma unroll
        for (int kt = 0; kt < 2; ++kt)
            a_hh[mt][kt] = cvt8_(W_hh + (mt * 16 + s) * 64 + kt * 32 + q * 8);
    {
        const float* hrow = (s == 1) ? W_p : ((s == 2) ? W_psi0 : W_psi);
#pragma unroll
        for (int kt = 0; kt < 2; ++kt) a_head[kt] = cvt8_(hrow + kt * 32 + q * 8);
    }

    f32x4 biasD[4], wihD[4];
#pragma unroll
    for (int mt = 0; mt < 4; ++mt) {
        const int r0 = mt * 16 + q * 4;
        float4 bi = *(const float4*)(b_ih + r0);
        float4 bh = *(const float4*)(b_hh + r0);
        float4 wi = *(const float4*)(W_ih + r0);
        biasD[mt][0] = bi.x + bh.x; biasD[mt][1] = bi.y + bh.y;
        biasD[mt][2] = bi.z + bh.z; biasD[mt][3] = bi.w + bh.w;
        wihD[mt][0] = wi.x; wihD[mt][1] = wi.y; wihD[mt][2] = wi.z; wihD[mt][3] = wi.w;
    }
    f32x4 headC;
    headC[0] = (q == 0) ? b_psi[0]  : 0.0f;
    headC[1] = (q == 0) ? b_p[0]    : 0.0f;
    headC[2] = (q == 0) ? b_psi0[0] : 0.0f;
    headC[3] = 0.0f;
    const float wpo = W_p[HDIM];

    const float* sxy_l = sxy + (size_t)site * (NYEARS - 1);
    const float* oxy_l = oxy + (size_t)site * (NYEARS * 2);

    // ==== recurrence: round t computes h_t and heads(h_{t-1}) ====
    for (int t = 1; t < NYEARS; ++t) {
        bf16x8 bf[2];
        bf[0] = read_bfrag_(&h_sh[s * 68 + 0  + q * 8]);
        bf[1] = read_bfrag_(&h_sh[s * 68 + 32 + q * 8]);

        f32x4 acc[4], accH = headC;
#pragma unroll
        for (int mt = 0; mt < 4; ++mt) acc[mt] = biasD[mt];
#pragma unroll
        for (int kt = 0; kt < 2; ++kt) {
#pragma unroll
            for (int mt = 0; mt < 4; ++mt)
                acc[mt] = __builtin_amdgcn_mfma_f32_16x16x32_bf16(a_hh[mt][kt], bf[kt], acc[mt], 0, 0, 0);
            accH = __builtin_amdgcn_mfma_f32_16x16x32_bf16(a_head[kt], bf[kt], accH, 0, 0, 0);
        }

        const float x = sxy_l[t - 1];
#pragma unroll
        for (int mt = 0; mt < 4; ++mt) {
            float v0 = fmaxf(fmaf(x, wihD[mt][0], acc[mt][0]), 0.0f);
            float v1 = fmaxf(fmaf(x, wihD[mt][1], acc[mt][1]), 0.0f);
            float v2 = fmaxf(fmaf(x, wihD[mt][2], acc[mt][2]), 0.0f);
            float v3 = fmaxf(fmaf(x, wihD[mt][3], acc[mt][3]), 0.0f);
            uint2 pk; pk.x = pack2_(v0, v1); pk.y = pack2_(v2, v3);
            *(uint2*)&h_sh[s * 68 + mt * 16 + q * 4] = pk;
        }

        if (q == 0) {
            // accH[0]=W_psi.h_{t-1}+b_psi, [1]=W_p.h_{t-1}+b_p, [2]=W_psi0.h_{t-1}+b_psi0
            float2 ox = *(const float2*)(oxy_l + (t - 1) * 2);
            float p0 = sigmoidf_(fmaf(wpo, ox.x, accH[1]));
            float p1 = sigmoidf_(fmaf(wpo, ox.y, accH[1]));
            float2 pp; pp.x = p0; pp.y = p1;
            *(float2*)&p_sh[s * 40 + (t - 1) * 2] = pp;
            if (t == 1) {
                out_psi0[site] = sigmoidf_(accH[2]);   // psi0 from h0
            } else {
                psi_sh[s * 19 + (t - 2)] = sigmoidf_(accH[0]);
            }
        }
    }

    // ==== final heads on h_19 ====
    {
        bf16x8 bf[2];
        bf[0] = read_bfrag_(&h_sh[s * 68 + 0  + q * 8]);
        bf[1] = read_bfrag_(&h_sh[s * 68 + 32 + q * 8]);
        f32x4 accH = headC;
#pragma unroll
        for (int kt = 0; kt < 2; ++kt)
            accH = __builtin_amdgcn_mfma_f32_16x16x32_bf16(a_head[kt], bf[kt], accH, 0, 0, 0);
        if (q == 0) {
            float2 ox = *(const float2*)(oxy_l + 19 * 2);
            float p0 = sigmoidf_(fmaf(wpo, ox.x, accH[1]));
            float p1 = sigmoidf_(fmaf(wpo, ox.y, accH[1]));
            float2 pp; pp.x = p0; pp.y = p1;
            *(float2*)&p_sh[s * 40 + 38] = pp;
            psi_sh[s * 19 + 18] = sigmoidf_(accH[0]);
        }
    }

    __syncthreads();

    // ==== coalesced writeback from LDS ====
#pragma unroll
    for (int r = 0; r < 5; ++r) {
        int i = r * 64 + lane;
        if (i < 16 * 19) out_psi[(size_t)base * 19 + i] = psi_sh[i];
    }
    // p region per block: 16*40 = 640 floats = 160 float4
    f32x4* pg = (f32x4*)(out_p + (size_t)base * 40);
    const f32x4* ps = (const f32x4*)p_sh;
#pragma unroll
    for (int r = 0; r < 3; ++r) {
        int i = r * 64 + lane;
        if (i < 160) pg[i] = ps[i];
    }
}

extern "C" void kernel_launch(void* const* d_in, const int* in_sizes, int n_in,
                              void* d_out, int out_size, void* d_ws, size_t ws_size,
                              hipStream_t stream) {
    const float* sxy0   = (const float*)d_in[0];
    const float* sxy    = (const float*)d_in[1];
    const float* oxy    = (const float*)d_in[2];
    const float* W_h0   = (const float*)d_in[3];
    const float* b_h0   = (const float*)d_in[4];
    const float* W_h1   = (const float*)d_in[5];
    const float* b_h1   = (const float*)d_in[6];
    const float* W_ih   = (const float*)d_in[7];
    const float* b_ih   = (const float*)d_in[8];
    const float* W_hh   = (const float*)d_in[9];
    const float* b_hh   = (const float*)d_in[10];
    const float* W_psi0 = (const float*)d_in[11];
    const float* b_psi0 = (const float*)d_in[12];
    const float* W_psi  = (const float*)d_in[13];
    const float* b_psi  = (const float*)d_in[14];
    const float* W_p    = (const float*)d_in[15];
    const float* b_p    = (const float*)d_in[16];

    float* out = (float*)d_out;

    dim3 block(64);
    dim3 grid(NSITES / 16);   // 6250 waves, 16 sites each
    rnet_kernel<<<grid, block, 0, stream>>>(
        sxy0, sxy, oxy, W_h0, b_h0, W_h1, b_h1, W_ih, b_ih, W_hh, b_hh,
        W_psi0, b_psi0, W_psi, b_psi, W_p, b_p, out);
}

// Round 5
// 152.710 us; speedup vs baseline: 5.4936x; 1.0975x over previous
//
#include <hip/hip_runtime.h>
#include <math.h>

#define NSITES 100000
#define NYEARS 20
#define HDIM 64

typedef __bf16 bf16x8 __attribute__((ext_vector_type(8)));
typedef float f32x4 __attribute__((ext_vector_type(4)));

__device__ __forceinline__ float sigmoidf_(float x) { return 1.0f / (1.0f + __expf(-x)); }
__device__ __forceinline__ float eluf_(float x) { return x > 0.0f ? x : expm1f(x); }

// load 8 consecutive f32 (32B-aligned) -> bf16x8 (RNE via __bf16 cast)
__device__ __forceinline__ bf16x8 cvt8_(const float* p) {
    float4 a = ((const float4*)p)[0];
    float4 b = ((const float4*)p)[1];
    bf16x8 r;
    r[0] = (__bf16)a.x; r[1] = (__bf16)a.y; r[2] = (__bf16)a.z; r[3] = (__bf16)a.w;
    r[4] = (__bf16)b.x; r[5] = (__bf16)b.y; r[6] = (__bf16)b.z; r[7] = (__bf16)b.w;
    return r;
}

__device__ __forceinline__ bf16x8 pack_bf_(f32x4 lo, f32x4 hi) {
    bf16x8 r;
    r[0] = (__bf16)lo[0]; r[1] = (__bf16)lo[1]; r[2] = (__bf16)lo[2]; r[3] = (__bf16)lo[3];
    r[4] = (__bf16)hi[0]; r[5] = (__bf16)hi[1]; r[6] = (__bf16)hi[2]; r[7] = (__bf16)hi[3];
    return r;
}

// One wave = 16 sites, MFMA 16x16x32 bf16 recurrence with PERMUTED output rows:
//   pi(32*kt + 8*q + 4*b + r) = 16*(2*kt+b) + 4*q + r
// With W_hh/W_h1/biases/W_ih rows permuted by pi, lane (q,s)'s D registers
// hold exactly the orig h rows {8q..8q+7} (acc[0],acc[1]) and {32+8q..+7}
// (acc[2],acc[3]) that its own next-round B-fragment needs:
//   bf[0] = pack(acc0, acc1), bf[1] = pack(acc2, acc3)  -- NO LDS round-trip.
// Heads (W_psi/W_p/W_psi0 as rows 0..2 of a 5th m-tile) stay unpermuted; raw
// logits buffered in LDS, sigmoid+oxy applied in a coalesced epilogue.
__global__ __launch_bounds__(64, 2)
void rnet_kernel(const float* __restrict__ sxy0,
                 const float* __restrict__ sxy,
                 const float* __restrict__ oxy,
                 const float* __restrict__ W_h0, const float* __restrict__ b_h0,
                 const float* __restrict__ W_h1, const float* __restrict__ b_h1,
                 const float* __restrict__ W_ih, const float* __restrict__ b_ih,
                 const float* __restrict__ W_hh, const float* __restrict__ b_hh,
                 const float* __restrict__ W_psi0, const float* __restrict__ b_psi0,
                 const float* __restrict__ W_psi, const float* __restrict__ b_psi,
                 const float* __restrict__ W_p, const float* __restrict__ b_p,
                 float* __restrict__ out)
{
    const int lane = threadIdx.x;       // 0..63
    const int s = lane & 15;            // site within wave / A-row within tile
    const int q = lane >> 4;            // quad
    const int sq = s >> 2, sr = s & 3;
    const int base = blockIdx.x * 16;   // NSITES = 6250*16 exactly
    const int site = base + s;

    __shared__ __align__(16) float pL_sh[16 * 20];    // raw p logits  [site][t]
    __shared__ __align__(16) float psiL_sh[16 * 19];  // raw psi logits [site][t]

    float* __restrict__ out_psi0 = out;                 // [N]
    float* __restrict__ out_psi  = out + NSITES;        // [N,19]
    float* __restrict__ out_p    = out + 20 * NSITES;   // [N,20,2]

    // ---- A fragments: W_hh rows loaded pre-permuted ----
    // A row (orig) for m-tile mt, lane row s: 32*(mt>>1) + 8*sq + 4*(mt&1) + sr
    bf16x8 a_hh[4][2];
#pragma unroll
    for (int mt = 0; mt < 4; ++mt) {
        const int ar = 32 * (mt >> 1) + 8 * sq + 4 * (mt & 1) + sr;
#pragma unroll
        for (int kt = 0; kt < 2; ++kt)
            a_hh[mt][kt] = cvt8_(W_hh + ar * 64 + kt * 32 + q * 8);
    }
    bf16x8 a_head[2];
    {
        const float* hrow = (s == 1) ? W_p : ((s == 2) ? W_psi0 : W_psi);
#pragma unroll
        for (int kt = 0; kt < 2; ++kt) a_head[kt] = cvt8_(hrow + kt * 32 + q * 8);
    }

    // ---- D constants at permuted row base: 32*(mt>>1) + 8*q + 4*(mt&1) ----
    f32x4 biasD[4], wihD[4];
#pragma unroll
    for (int mt = 0; mt < 4; ++mt) {
        const int dr = 32 * (mt >> 1) + 8 * q + 4 * (mt & 1);
        float4 bi = *(const float4*)(b_ih + dr);
        float4 bh = *(const float4*)(b_hh + dr);
        float4 wi = *(const float4*)(W_ih + dr);
        biasD[mt][0] = bi.x + bh.x; biasD[mt][1] = bi.y + bh.y;
        biasD[mt][2] = bi.z + bh.z; biasD[mt][3] = bi.w + bh.w;
        wihD[mt][0] = wi.x; wihD[mt][1] = wi.y; wihD[mt][2] = wi.z; wihD[mt][3] = wi.w;
    }
    f32x4 headC;
    headC[0] = (q == 0) ? b_psi[0]  : 0.0f;
    headC[1] = (q == 0) ? b_p[0]    : 0.0f;
    headC[2] = (q == 0) ? b_psi0[0] : 0.0f;
    headC[3] = 0.0f;
    const float wpo = W_p[HDIM];

    // ---- prefetch all per-site x values (kills in-loop global loads) ----
    float xs[NYEARS - 1];
    {
        const float* sxy_l = sxy + (size_t)site * (NYEARS - 1);
#pragma unroll
        for (int i = 0; i < NYEARS - 1; ++i) xs[i] = sxy_l[i];
    }

    // ---- h0: hs = elu(s0*W_h0+b_h0) in B layout; h0 via permuted W_h1 ----
    bf16x8 bf[2];
    {
        const float s0v = sxy0[site];
        bf16x8 bf0[2];
#pragma unroll
        for (int kt = 0; kt < 2; ++kt) {
            const float* wp = W_h0 + kt * 32 + q * 8;
            const float* bp = b_h0 + kt * 32 + q * 8;
            float4 w0 = ((const float4*)wp)[0], w1 = ((const float4*)wp)[1];
            float4 c0 = ((const float4*)bp)[0], c1 = ((const float4*)bp)[1];
            float v[8];
            v[0] = eluf_(fmaf(s0v, w0.x, c0.x)); v[1] = eluf_(fmaf(s0v, w0.y, c0.y));
            v[2] = eluf_(fmaf(s0v, w0.z, c0.z)); v[3] = eluf_(fmaf(s0v, w0.w, c0.w));
            v[4] = eluf_(fmaf(s0v, w1.x, c1.x)); v[5] = eluf_(fmaf(s0v, w1.y, c1.y));
            v[6] = eluf_(fmaf(s0v, w1.z, c1.z)); v[7] = eluf_(fmaf(s0v, w1.w, c1.w));
#pragma unroll
            for (int j = 0; j < 8; ++j) bf0[kt][j] = (__bf16)v[j];
        }

        f32x4 acc[4];
#pragma unroll
        for (int mt = 0; mt < 4; ++mt) {
            const int dr = 32 * (mt >> 1) + 8 * q + 4 * (mt & 1);
            float4 b1 = *(const float4*)(b_h1 + dr);
            acc[mt][0] = b1.x; acc[mt][1] = b1.y; acc[mt][2] = b1.z; acc[mt][3] = b1.w;
        }
#pragma unroll
        for (int kt = 0; kt < 2; ++kt)
#pragma unroll
            for (int mt = 0; mt < 4; ++mt) {
                const int ar = 32 * (mt >> 1) + 8 * sq + 4 * (mt & 1) + sr;
                bf16x8 a = cvt8_(W_h1 + ar * 64 + kt * 32 + q * 8);
                acc[mt] = __builtin_amdgcn_mfma_f32_16x16x32_bf16(a, bf0[kt], acc[mt], 0, 0, 0);
            }
        f32x4 e[4];
#pragma unroll
        for (int mt = 0; mt < 4; ++mt)
#pragma unroll
            for (int r = 0; r < 4; ++r) e[mt][r] = eluf_(acc[mt][r]);
        bf[0] = pack_bf_(e[0], e[1]);
        bf[1] = pack_bf_(e[2], e[3]);
    }

    // ---- recurrence: round t consumes bf = h_{t-1}, produces bf = h_t ----
#pragma unroll
    for (int t = 1; t < NYEARS; ++t) {
        f32x4 acc[4], accH = headC;
#pragma unroll
        for (int mt = 0; mt < 4; ++mt) acc[mt] = biasD[mt];
#pragma unroll
        for (int kt = 0; kt < 2; ++kt) {
#pragma unroll
            for (int mt = 0; mt < 4; ++mt)
                acc[mt] = __builtin_amdgcn_mfma_f32_16x16x32_bf16(a_hh[mt][kt], bf[kt], acc[mt], 0, 0, 0);
            accH = __builtin_amdgcn_mfma_f32_16x16x32_bf16(a_head[kt], bf[kt], accH, 0, 0, 0);
        }

        const float x = xs[t - 1];
        f32x4 hn[4];
#pragma unroll
        for (int mt = 0; mt < 4; ++mt)
#pragma unroll
            for (int r = 0; r < 4; ++r)
                hn[mt][r] = fmaxf(fmaf(x, wihD[mt][r], acc[mt][r]), 0.0f);
        bf[0] = pack_bf_(hn[0], hn[1]);
        bf[1] = pack_bf_(hn[2], hn[3]);

        if (q == 0) {
            // accH over h_{t-1}: p slot t-1; psi slot t-2 (t>=2); psi0 at t==1
            pL_sh[s * 20 + (t - 1)] = accH[1];
            if (t == 1) {
                out_psi0[site] = sigmoidf_(accH[2]);
            } else {
                psiL_sh[s * 19 + (t - 2)] = accH[0];
            }
        }
    }

    // ---- final heads on h_19 ----
    {
        f32x4 accH = headC;
#pragma unroll
        for (int kt = 0; kt < 2; ++kt)
            accH = __builtin_amdgcn_mfma_f32_16x16x32_bf16(a_head[kt], bf[kt], accH, 0, 0, 0);
        if (q == 0) {
            pL_sh[s * 20 + 19] = accH[1];
            psiL_sh[s * 19 + 18] = accH[0];
        }
    }

    __syncthreads();

    // ---- epilogue: sigmoid + oxy, fully coalesced, div-free indexing ----
    // psi: out flat index i = site*19 + t  ==  psiL_sh flat index
#pragma unroll
    for (int r = 0; r < 5; ++r) {
        int i = r * 64 + lane;
        if (i < 16 * 19)
            out_psi[(size_t)base * 19 + i] = sigmoidf_(psiL_sh[i]);
    }
    // p: out flat i = site*40 + t*2 + j; logit index = i>>1 = site*20 + t
    const float* oxy_b = oxy + (size_t)base * 40;
    float* outp_b = out_p + (size_t)base * 40;
#pragma unroll
    for (int r = 0; r < 10; ++r) {
        int i = r * 64 + lane;
        float lg = pL_sh[i >> 1];
        outp_b[i] = sigmoidf_(fmaf(wpo, oxy_b[i], lg));
    }
}

extern "C" void kernel_launch(void* const* d_in, const int* in_sizes, int n_in,
                              void* d_out, int out_size, void* d_ws, size_t ws_size,
                              hipStream_t stream) {
    const float* sxy0   = (const float*)d_in[0];
    const float* sxy    = (const float*)d_in[1];
    const float* oxy    = (const float*)d_in[2];
    const float* W_h0   = (const float*)d_in[3];
    const float* b_h0   = (const float*)d_in[4];
    const float* W_h1   = (const float*)d_in[5];
    const float* b_h1   = (const float*)d_in[6];
    const float* W_ih   = (const float*)d_in[7];
    const float* b_ih   = (const float*)d_in[8];
    const float* W_hh   = (const float*)d_in[9];
    const float* b_hh   = (const float*)d_in[10];
    const float* W_psi0 = (const float*)d_in[11];
    const float* b_psi0 = (const float*)d_in[12];
    const float* W_psi  = (const float*)d_in[13];
    const float* b_psi  = (const float*)d_in[14];
    const float* W_p    = (const float*)d_in[15];
    const float* b_p    = (const float*)d_in[16];

    float* out = (float*)d_out;

    dim3 block(64);
    dim3 grid(NSITES / 16);   // 6250 waves, 16 sites each
    rnet_kernel<<<grid, block, 0, stream>>>(
        sxy0, sxy, oxy, W_h0, b_h0, W_h1, b_h1, W_ih, b_ih, W_hh, b_hh,
        W_psi0, b_psi0, W_psi, b_psi, W_p, b_p, out);
}

// Round 6
// 149.423 us; speedup vs baseline: 5.6145x; 1.0220x over previous
//
#include <hip/hip_runtime.h>
#include <math.h>

#define NSITES 100000
#define NYEARS 20
#define HDIM 64

typedef __bf16 bf16x8 __attribute__((ext_vector_type(8)));
typedef float f32x4 __attribute__((ext_vector_type(4)));

__device__ __forceinline__ float sigmoidf_(float x) { return 1.0f / (1.0f + __expf(-x)); }
__device__ __forceinline__ float eluf_(float x) { return x > 0.0f ? x : expm1f(x); }

// load 8 consecutive f32 (32B-aligned) -> bf16x8 (RNE via __bf16 cast)
__device__ __forceinline__ bf16x8 cvt8_(const float* p) {
    float4 a = ((const float4*)p)[0];
    float4 b = ((const float4*)p)[1];
    bf16x8 r;
    r[0] = (__bf16)a.x; r[1] = (__bf16)a.y; r[2] = (__bf16)a.z; r[3] = (__bf16)a.w;
    r[4] = (__bf16)b.x; r[5] = (__bf16)b.y; r[6] = (__bf16)b.z; r[7] = (__bf16)b.w;
    return r;
}

__device__ __forceinline__ bf16x8 pack_bf_(f32x4 lo, f32x4 hi) {
    bf16x8 r;
    r[0] = (__bf16)lo[0]; r[1] = (__bf16)lo[1]; r[2] = (__bf16)lo[2]; r[3] = (__bf16)lo[3];
    r[4] = (__bf16)hi[0]; r[5] = (__bf16)hi[1]; r[6] = (__bf16)hi[2]; r[7] = (__bf16)hi[3];
    return r;
}

// One wave = TWO independent 16-site recurrences (G=2), interleaved for ILP:
// the serial chain MFMA->MFMA->pack->MFMA of group 0 is filled by group 1's
// independent instructions. Weight fragments are shared between groups.
// Permuted-output-row trick (R5): pi(32kt+8q+4b+r)=16(2kt+b)+4q+r makes lane
// (q,s)'s D registers exactly its own next-round B-fragment -- no LDS in loop.
// Heads = 5th m-tile (W_psi/W_p/W_psi0 rows); raw logits -> LDS -> epilogue.
__global__ __launch_bounds__(64, 2)
void rnet_kernel(const float* __restrict__ sxy0,
                 const float* __restrict__ sxy,
                 const float* __restrict__ oxy,
                 const float* __restrict__ W_h0, const float* __restrict__ b_h0,
                 const float* __restrict__ W_h1, const float* __restrict__ b_h1,
                 const float* __restrict__ W_ih, const float* __restrict__ b_ih,
                 const float* __restrict__ W_hh, const float* __restrict__ b_hh,
                 const float* __restrict__ W_psi0, const float* __restrict__ b_psi0,
                 const float* __restrict__ W_psi, const float* __restrict__ b_psi,
                 const float* __restrict__ W_p, const float* __restrict__ b_p,
                 float* __restrict__ out)
{
    const int lane = threadIdx.x;       // 0..63
    const int s = lane & 15;            // site within group / A-row within tile
    const int q = lane >> 4;            // quad
    const int sq = s >> 2, sr = s & 3;
    const int base = blockIdx.x * 32;   // NSITES = 3125*32 exactly
    const int site0 = base + s;         // group 0
    const int site1 = base + 16 + s;    // group 1

    __shared__ __align__(16) float pL_sh[32 * 20];    // raw p logits  [site][t]
    __shared__ __align__(16) float psiL_sh[32 * 19];  // raw psi logits [site][t]

    float* __restrict__ out_psi0 = out;                 // [N]
    float* __restrict__ out_psi  = out + NSITES;        // [N,19]
    float* __restrict__ out_p    = out + 20 * NSITES;   // [N,20,2]

    // ---- A fragments (shared by both groups): W_hh rows pre-permuted ----
    bf16x8 a_hh[4][2];
#pragma unroll
    for (int mt = 0; mt < 4; ++mt) {
        const int ar = 32 * (mt >> 1) + 8 * sq + 4 * (mt & 1) + sr;
#pragma unroll
        for (int kt = 0; kt < 2; ++kt)
            a_hh[mt][kt] = cvt8_(W_hh + ar * 64 + kt * 32 + q * 8);
    }
    bf16x8 a_head[2];
    {
        const float* hrow = (s == 1) ? W_p : ((s == 2) ? W_psi0 : W_psi);
#pragma unroll
        for (int kt = 0; kt < 2; ++kt) a_head[kt] = cvt8_(hrow + kt * 32 + q * 8);
    }

    // ---- D constants at permuted row base: 32*(mt>>1) + 8*q + 4*(mt&1) ----
    f32x4 biasD[4], wihD[4];
#pragma unroll
    for (int mt = 0; mt < 4; ++mt) {
        const int dr = 32 * (mt >> 1) + 8 * q + 4 * (mt & 1);
        float4 bi = *(const float4*)(b_ih + dr);
        float4 bh = *(const float4*)(b_hh + dr);
        float4 wi = *(const float4*)(W_ih + dr);
        biasD[mt][0] = bi.x + bh.x; biasD[mt][1] = bi.y + bh.y;
        biasD[mt][2] = bi.z + bh.z; biasD[mt][3] = bi.w + bh.w;
        wihD[mt][0] = wi.x; wihD[mt][1] = wi.y; wihD[mt][2] = wi.z; wihD[mt][3] = wi.w;
    }
    f32x4 headC;
    headC[0] = (q == 0) ? b_psi[0]  : 0.0f;
    headC[1] = (q == 0) ? b_p[0]    : 0.0f;
    headC[2] = (q == 0) ? b_psi0[0] : 0.0f;
    headC[3] = 0.0f;
    const float wpo = W_p[HDIM];

    // ---- prefetch per-site x values for both groups ----
    float xs[2][NYEARS - 1];
#pragma unroll
    for (int i = 0; i < NYEARS - 1; ++i) {
        xs[0][i] = sxy[(size_t)site0 * (NYEARS - 1) + i];
        xs[1][i] = sxy[(size_t)site1 * (NYEARS - 1) + i];
    }

    // ---- h0 for both groups (shared W_h0/b_h0/W_h1/b_h1 loads) ----
    bf16x8 bf[2][2];   // [group][kt]
    {
        float s0v[2];
        s0v[0] = sxy0[site0];
        s0v[1] = sxy0[site1];
        bf16x8 bf0[2][2];
#pragma unroll
        for (int kt = 0; kt < 2; ++kt) {
            const float* wp = W_h0 + kt * 32 + q * 8;
            const float* bp = b_h0 + kt * 32 + q * 8;
            float4 w0 = ((const float4*)wp)[0], w1 = ((const float4*)wp)[1];
            float4 c0 = ((const float4*)bp)[0], c1 = ((const float4*)bp)[1];
#pragma unroll
            for (int g = 0; g < 2; ++g) {
                const float sv = s0v[g];
                float v[8];
                v[0] = eluf_(fmaf(sv, w0.x, c0.x)); v[1] = eluf_(fmaf(sv, w0.y, c0.y));
                v[2] = eluf_(fmaf(sv, w0.z, c0.z)); v[3] = eluf_(fmaf(sv, w0.w, c0.w));
                v[4] = eluf_(fmaf(sv, w1.x, c1.x)); v[5] = eluf_(fmaf(sv, w1.y, c1.y));
                v[6] = eluf_(fmaf(sv, w1.z, c1.z)); v[7] = eluf_(fmaf(sv, w1.w, c1.w));
#pragma unroll
                for (int j = 0; j < 8; ++j) bf0[g][kt][j] = (__bf16)v[j];
            }
        }

        f32x4 acc[2][4];
#pragma unroll
        for (int mt = 0; mt < 4; ++mt) {
            const int dr = 32 * (mt >> 1) + 8 * q + 4 * (mt & 1);
            float4 b1 = *(const float4*)(b_h1 + dr);
#pragma unroll
            for (int g = 0; g < 2; ++g) {
                acc[g][mt][0] = b1.x; acc[g][mt][1] = b1.y;
                acc[g][mt][2] = b1.z; acc[g][mt][3] = b1.w;
            }
        }
#pragma unroll
        for (int kt = 0; kt < 2; ++kt)
#pragma unroll
            for (int mt = 0; mt < 4; ++mt) {
                const int ar = 32 * (mt >> 1) + 8 * sq + 4 * (mt & 1) + sr;
                bf16x8 a = cvt8_(W_h1 + ar * 64 + kt * 32 + q * 8);
#pragma unroll
                for (int g = 0; g < 2; ++g)
                    acc[g][mt] = __builtin_amdgcn_mfma_f32_16x16x32_bf16(a, bf0[g][kt], acc[g][mt], 0, 0, 0);
            }
#pragma unroll
        for (int g = 0; g < 2; ++g) {
            f32x4 e[4];
#pragma unroll
            for (int mt = 0; mt < 4; ++mt)
#pragma unroll
                for (int r = 0; r < 4; ++r) e[mt][r] = eluf_(acc[g][mt][r]);
            bf[g][0] = pack_bf_(e[0], e[1]);
            bf[g][1] = pack_bf_(e[2], e[3]);
        }
    }

    // ---- recurrence: both groups per round, independent chains ----
#pragma unroll
    for (int t = 1; t < NYEARS; ++t) {
        f32x4 acc[2][4], accH[2];
#pragma unroll
        for (int g = 0; g < 2; ++g) {
            accH[g] = headC;
#pragma unroll
            for (int mt = 0; mt < 4; ++mt) acc[g][mt] = biasD[mt];
        }
#pragma unroll
        for (int kt = 0; kt < 2; ++kt) {
#pragma unroll
            for (int mt = 0; mt < 4; ++mt)
#pragma unroll
                for (int g = 0; g < 2; ++g)
                    acc[g][mt] = __builtin_amdgcn_mfma_f32_16x16x32_bf16(a_hh[mt][kt], bf[g][kt], acc[g][mt], 0, 0, 0);
#pragma unroll
            for (int g = 0; g < 2; ++g)
                accH[g] = __builtin_amdgcn_mfma_f32_16x16x32_bf16(a_head[kt], bf[g][kt], accH[g], 0, 0, 0);
        }

#pragma unroll
        for (int g = 0; g < 2; ++g) {
            const float x = xs[g][t - 1];
            f32x4 hn[4];
#pragma unroll
            for (int mt = 0; mt < 4; ++mt)
#pragma unroll
                for (int r = 0; r < 4; ++r)
                    hn[mt][r] = fmaxf(fmaf(x, wihD[mt][r], acc[g][mt][r]), 0.0f);
            bf[g][0] = pack_bf_(hn[0], hn[1]);
            bf[g][1] = pack_bf_(hn[2], hn[3]);

            if (q == 0) {
                const int ls = g * 16 + s;
                pL_sh[ls * 20 + (t - 1)] = accH[g][1];
                if (t == 1) {
                    out_psi0[base + g * 16 + s] = sigmoidf_(accH[g][2]);
                } else {
                    psiL_sh[ls * 19 + (t - 2)] = accH[g][0];
                }
            }
        }
    }

    // ---- final heads on h_19 ----
#pragma unroll
    for (int g = 0; g < 2; ++g) {
        f32x4 accH = headC;
#pragma unroll
        for (int kt = 0; kt < 2; ++kt)
            accH = __builtin_amdgcn_mfma_f32_16x16x32_bf16(a_head[kt], bf[g][kt], accH, 0, 0, 0);
        if (q == 0) {
            const int ls = g * 16 + s;
            pL_sh[ls * 20 + 19] = accH[1];
            psiL_sh[ls * 19 + 18] = accH[0];
        }
    }

    __syncthreads();

    // ---- epilogue: sigmoid + oxy, coalesced, div-free indexing ----
    // psi: 32*19 = 608 floats; out flat i = base*19 + i
#pragma unroll
    for (int r = 0; r < 10; ++r) {
        int i = r * 64 + lane;
        if (i < 32 * 19)
            out_psi[(size_t)base * 19 + i] = sigmoidf_(psiL_sh[i]);
    }
    // p: 32*40 = 1280 floats = 320 float4; logit index = float_i >> 1
    const float4* oxy_b = (const float4*)(oxy + (size_t)base * 40);
    float4* outp_b = (float4*)(out_p + (size_t)base * 40);
#pragma unroll
    for (int r = 0; r < 5; ++r) {
        int i4 = r * 64 + lane;            // [0,320)
        float4 ox = oxy_b[i4];
        float lg0 = pL_sh[i4 * 2];
        float lg1 = pL_sh[i4 * 2 + 1];
        float4 pv;
        pv.x = sigmoidf_(fmaf(wpo, ox.x, lg0));
        pv.y = sigmoidf_(fmaf(wpo, ox.y, lg0));
        pv.z = sigmoidf_(fmaf(wpo, ox.z, lg1));
        pv.w = sigmoidf_(fmaf(wpo, ox.w, lg1));
        outp_b[i4] = pv;
    }
}

extern "C" void kernel_launch(void* const* d_in, const int* in_sizes, int n_in,
                              void* d_out, int out_size, void* d_ws, size_t ws_size,
                              hipStream_t stream) {
    const float* sxy0   = (const float*)d_in[0];
    const float* sxy    = (const float*)d_in[1];
    const float* oxy    = (const float*)d_in[2];
    const float* W_h0   = (const float*)d_in[3];
    const float* b_h0   = (const float*)d_in[4];
    const float* W_h1   = (const float*)d_in[5];
    const float* b_h1   = (const float*)d_in[6];
    const float* W_ih   = (const float*)d_in[7];
    const float* b_ih   = (const float*)d_in[8];
    const float* W_hh   = (const float*)d_in[9];
    const float* b_hh   = (const float*)d_in[10];
    const float* W_psi0 = (const float*)d_in[11];
    const float* b_psi0 = (const float*)d_in[12];
    const float* W_psi  = (const float*)d_in[13];
    const float* b_psi  = (const float*)d_in[14];
    const float* W_p    = (const float*)d_in[15];
    const float* b_p    = (const float*)d_in[16];

    float* out = (float*)d_out;

    dim3 block(64);
    dim3 grid(NSITES / 32);   // 3125 waves, 32 sites each (2 groups of 16)
    rnet_kernel<<<grid, block, 0, stream>>>(
        sxy0, sxy, oxy, W_h0, b_h0, W_h1, b_h1, W_ih, b_ih, W_hh, b_hh,
        W_psi0, b_psi0, W_psi, b_psi, W_p, b_p, out);
}